// Round 1
// baseline (1158.549 us; speedup 1.0000x reference)
//
#include <hip/hip_runtime.h>

typedef __bf16 bf16_t;
typedef __bf16 bf16x8 __attribute__((ext_vector_type(8)));
typedef __bf16 bf16x4 __attribute__((ext_vector_type(4)));
typedef float  f32x4  __attribute__((ext_vector_type(4)));

#define MFMA16(a, b, c) __builtin_amdgcn_mfma_f32_16x16x32_bf16((a), (b), (c), 0, 0, 0)

__device__ __forceinline__ void async_load16(const void* g, void* l) {
    __builtin_amdgcn_global_load_lds(
        (const __attribute__((address_space(1))) void*)g,
        (__attribute__((address_space(3))) void*)l, 16, 0, 0);
}

// ---------------------------------------------------------------- fp32 -> bf16
__global__ void cvt_f32_to_bf16(const float* __restrict__ src, bf16_t* __restrict__ dst, int n) {
    int stride4 = gridDim.x * blockDim.x * 4;
    for (int j = (blockIdx.x * blockDim.x + threadIdx.x) * 4; j < n; j += stride4) {
        float4 v = *(const float4*)(src + j);
        bf16x4 o = { (bf16_t)v.x, (bf16_t)v.y, (bf16_t)v.z, (bf16_t)v.w };
        *(bf16x4*)(dst + j) = o;
    }
}

// ---------------------------------------------------------------- GEMM (B^T): C[m,n] = sum_k A[m,k]*B[n,k]
__device__ __forceinline__ void storeC(float* C, size_t idx, float v)  { C[idx] = v; }
__device__ __forceinline__ void storeC(bf16_t* C, size_t idx, float v) { C[idx] = (bf16_t)v; }

template <typename OT>
__global__ __launch_bounds__(256) void gemm_bt(const bf16_t* __restrict__ A,
                                               const bf16_t* __restrict__ B,
                                               OT* __restrict__ C,
                                               int M, int N, int K) {
    __shared__ __align__(16) bf16_t As[128][32];
    __shared__ __align__(16) bf16_t Bs[128][32];
    const int lane = threadIdx.x & 63;
    const int wid  = threadIdx.x >> 6;
    const int wr   = wid >> 1, wc = wid & 1;
    const int lrow = lane & 15, lhi = lane >> 4;
    const size_t m0 = (size_t)blockIdx.y * 128, n0 = (size_t)blockIdx.x * 128;
    const int srow = lane >> 2;         // staging row within 16-row stripe
    const int scol = (lane & 3) * 8;    // staging k-element offset

    const f32x4 vzero = {0.f, 0.f, 0.f, 0.f};
    f32x4 acc[4][4];
#pragma unroll
    for (int i = 0; i < 4; i++)
#pragma unroll
        for (int j = 0; j < 4; j++) acc[i][j] = vzero;

    for (int k0 = 0; k0 < K; k0 += 32) {
#pragma unroll
        for (int c = 0; c < 2; ++c) {
            int ra = wid * 32 + c * 16;
            async_load16(A + (m0 + ra + srow) * (size_t)K + k0 + scol, &As[ra][0]);
            async_load16(B + (n0 + ra + srow) * (size_t)K + k0 + scol, &Bs[ra][0]);
        }
        __syncthreads();
        bf16x8 af[4], bfr[4];
#pragma unroll
        for (int i = 0; i < 4; i++) af[i]  = *(const bf16x8*)(&As[wr * 64 + i * 16 + lrow][lhi * 8]);
#pragma unroll
        for (int j = 0; j < 4; j++) bfr[j] = *(const bf16x8*)(&Bs[wc * 64 + j * 16 + lrow][lhi * 8]);
#pragma unroll
        for (int i = 0; i < 4; i++)
#pragma unroll
            for (int j = 0; j < 4; j++)
                acc[i][j] = MFMA16(af[i], bfr[j], acc[i][j]);
        __syncthreads();
    }
#pragma unroll
    for (int i = 0; i < 4; i++)
#pragma unroll
        for (int j = 0; j < 4; j++)
#pragma unroll
            for (int r = 0; r < 4; r++) {
                size_t row = m0 + wr * 64 + i * 16 + lhi * 4 + r;
                size_t col = n0 + wc * 64 + j * 16 + lrow;
                storeC(C, row * (size_t)N + col, acc[i][j][r]);
            }
}

// ---------------------------------------------------------------- RoPE + scatter q/k
// fused: [4096][6144] bf16, col = kv*768 + slot*128 + d (slot 0..3 = q heads, 4 = k, 5 = v)
__global__ void rope_scatter(const bf16_t* __restrict__ fused, const int* __restrict__ pos_ids,
                             bf16_t* __restrict__ Q, bf16_t* __restrict__ Kb) {
    const int token = blockIdx.x;               // b*2048 + s
    const int b = token >> 11, s = token & 2047;
    const int d = threadIdx.x;                  // 0..63
    const float pos = (float)pos_ids[token];
    const float inv = __expf(-(float)d * (9.210340371976184f / 64.0f));  // 10000^{-d/64}
    float sn, c;
    sincosf(pos * inv, &sn, &c);
    const bf16_t* frow = fused + (size_t)token * 6144;
    for (int it = 0; it < 5; ++it) {
        int ss = it * 8 + threadIdx.y;          // 0..39: 32 q heads then 8 k heads
        int col;
        bf16_t* outp;
        if (ss < 32) {
            int h = ss, kv = h >> 2, gi = h & 3;
            col  = kv * 768 + gi * 128 + d;
            outp = Q + (((size_t)b * 32 + h) * 2048 + s) * 128 + d;
        } else {
            int kv = ss - 32;
            col  = kv * 768 + 512 + d;
            outp = Kb + (((size_t)b * 8 + kv) * 2048 + s) * 128 + d;
        }
        float x0 = (float)frow[col];
        float x1 = (float)frow[col + 64];
        outp[0]  = (bf16_t)(x0 * c - x1 * sn);
        outp[64] = (bf16_t)(x1 * c + x0 * sn);
    }
}

// ---------------------------------------------------------------- V transpose: fused v-cols -> Vt[b][kv][d][s]
__global__ void v_transpose(const bf16_t* __restrict__ fused, bf16_t* __restrict__ Vt) {
    __shared__ bf16_t tile[32][33];
    const int s0 = blockIdx.x * 32;     // token tile
    const int d0 = blockIdx.y * 32;     // dim tile
    const int bk = blockIdx.z;          // b*8 + kv
    const int b = bk >> 3, kv = bk & 7;
    const int col0 = kv * 768 + 640 + d0;
    const int tx = threadIdx.x, ty = threadIdx.y;
#pragma unroll
    for (int i = 0; i < 4; i++) {
        int sy = ty + i * 8;
        tile[sy][tx] = fused[((size_t)b * 2048 + s0 + sy) * 6144 + col0 + tx];
    }
    __syncthreads();
#pragma unroll
    for (int i = 0; i < 4; i++) {
        int dy = ty + i * 8;
        Vt[((size_t)bk * 128 + d0 + dy) * 2048 + s0 + tx] = tile[tx][dy];
    }
}

// ---------------------------------------------------------------- flash attention (causal, GQA)
// Q: [B][32][S][128], K: [B][8][S][128], Vt: [B][8][128][S], ctx: [B*S][4096] (col = h*128+d)
__global__ __launch_bounds__(64) void attn_fwd(const bf16_t* __restrict__ Q,
                                               const bf16_t* __restrict__ Kb,
                                               const bf16_t* __restrict__ Vt,
                                               bf16_t* __restrict__ ctx) {
    const int lane = threadIdx.x;
    const int qt = blockIdx.x, h = blockIdx.y, b = blockIdx.z;
    const int q0 = qt * 16;
    const int kvh = h >> 2;
    const int lrow = lane & 15, lhi = lane >> 4;

    const bf16_t* qbase = Q  + (((size_t)b * 32 + h) * 2048 + q0) * 128;
    const bf16_t* kbase = Kb + (((size_t)b * 8 + kvh) * 2048) * 128;
    const bf16_t* vbase = Vt + (((size_t)b * 8 + kvh) * 128) * 2048;

    __shared__ __align__(16) bf16_t P_lds[16][32];
    const f32x4 vzero = {0.f, 0.f, 0.f, 0.f};
    const float scale = 0.08838834764831845f;   // 1/sqrt(128)

    bf16x8 qf[4];
#pragma unroll
    for (int kk = 0; kk < 4; kk++)
        qf[kk] = *(const bf16x8*)(qbase + (size_t)lrow * 128 + kk * 32 + lhi * 8);

    f32x4 o[8];
#pragma unroll
    for (int j = 0; j < 8; j++) o[j] = vzero;
    float mrow[4], lsum[4];
#pragma unroll
    for (int r = 0; r < 4; r++) { mrow[r] = -1e30f; lsum[r] = 0.f; }

    for (int kv0 = 0; kv0 < q0 + 16; kv0 += 32) {
        f32x4 sacc[2];
        sacc[0] = vzero; sacc[1] = vzero;
#pragma unroll
        for (int kk = 0; kk < 4; kk++) {
            bf16x8 kf0 = *(const bf16x8*)(kbase + (size_t)(kv0 + lrow) * 128 + kk * 32 + lhi * 8);
            bf16x8 kf1 = *(const bf16x8*)(kbase + (size_t)(kv0 + 16 + lrow) * 128 + kk * 32 + lhi * 8);
            sacc[0] = MFMA16(qf[kk], kf0, sacc[0]);
            sacc[1] = MFMA16(qf[kk], kf1, sacc[1]);
        }
        const bool needmask = (kv0 + 31 > q0);
#pragma unroll
        for (int t = 0; t < 2; t++)
#pragma unroll
            for (int r = 0; r < 4; r++) {
                float sv = sacc[t][r] * scale;
                if (needmask) {
                    int kt = kv0 + t * 16 + lrow;
                    int qg = q0 + lhi * 4 + r;
                    if (kt > qg) sv = -1e30f;
                }
                sacc[t][r] = sv;
            }
        float pv[2][4];
#pragma unroll
        for (int r = 0; r < 4; r++) {
            float mx = fmaxf(sacc[0][r], sacc[1][r]);
#pragma unroll
            for (int off = 8; off >= 1; off >>= 1) mx = fmaxf(mx, __shfl_xor(mx, off, 64));
            float newm = fmaxf(mrow[r], mx);
            float corr = __expf(mrow[r] - newm);
            mrow[r] = newm;
            float p0 = __expf(sacc[0][r] - newm);
            float p1 = __expf(sacc[1][r] - newm);
            pv[0][r] = p0; pv[1][r] = p1;
            float ps = p0 + p1;
#pragma unroll
            for (int off = 8; off >= 1; off >>= 1) ps += __shfl_xor(ps, off, 64);
            lsum[r] = lsum[r] * corr + ps;
#pragma unroll
            for (int j = 0; j < 8; j++) o[j][r] *= corr;
        }
#pragma unroll
        for (int t = 0; t < 2; t++)
#pragma unroll
            for (int r = 0; r < 4; r++)
                P_lds[lhi * 4 + r][t * 16 + lrow] = (bf16_t)pv[t][r];
        __syncthreads();
        bf16x8 pa = *(const bf16x8*)(&P_lds[lrow][lhi * 8]);
#pragma unroll
        for (int j = 0; j < 8; j++) {
            bf16x8 vf = *(const bf16x8*)(vbase + (size_t)(j * 16 + lrow) * 2048 + kv0 + lhi * 8);
            o[j] = MFMA16(pa, vf, o[j]);
        }
        __syncthreads();
    }
    bf16_t* cbase = ctx + ((size_t)(b * 2048 + q0)) * 4096 + h * 128;
#pragma unroll
    for (int j = 0; j < 8; j++)
#pragma unroll
        for (int r = 0; r < 4; r++) {
            float val = o[j][r] / lsum[r];
            cbase[(size_t)(lhi * 4 + r) * 4096 + j * 16 + lrow] = (bf16_t)val;
        }
}

// ---------------------------------------------------------------- launch
extern "C" void kernel_launch(void* const* d_in, const int* in_sizes, int n_in,
                              void* d_out, int out_size, void* d_ws, size_t ws_size,
                              hipStream_t stream) {
    const float* hs   = (const float*)d_in[0];
    const int*   pos  = (const int*)d_in[1];
    const float* wqkv = (const float*)d_in[2];
    const float* wd   = (const float*)d_in[3];
    float* out = (float*)d_out;
    char* ws = (char*)d_ws;

    // workspace layout (bytes); total 184,549,376
    bf16_t* Xb    = (bf16_t*)(ws + 0ull);           // 33,554,432   (later reused as Q)
    bf16_t* Wqkvb = (bf16_t*)(ws + 33554432ull);    // 50,331,648
    bf16_t* Wdb   = (bf16_t*)(ws + 83886080ull);    // 33,554,432
    bf16_t* fused = (bf16_t*)(ws + 117440512ull);   // 50,331,648   (later reused as ctx)
    bf16_t* Kb    = (bf16_t*)(ws + 167772160ull);   // 8,388,608
    bf16_t* Vt    = (bf16_t*)(ws + 176160768ull);   // 8,388,608
    bf16_t* Qb    = Xb;
    bf16_t* ctx   = fused;

    cvt_f32_to_bf16<<<2048, 256, 0, stream>>>(hs,   Xb,    16777216);
    cvt_f32_to_bf16<<<2048, 256, 0, stream>>>(wqkv, Wqkvb, 25165824);
    cvt_f32_to_bf16<<<2048, 256, 0, stream>>>(wd,   Wdb,   16777216);

    gemm_bt<bf16_t><<<dim3(48, 32), 256, 0, stream>>>(Xb, Wqkvb, fused, 4096, 6144, 4096);

    rope_scatter<<<4096, dim3(64, 8), 0, stream>>>(fused, pos, Qb, Kb);
    v_transpose<<<dim3(64, 4, 16), dim3(32, 8), 0, stream>>>(fused, Vt);

    attn_fwd<<<dim3(128, 32, 2), 64, 0, stream>>>(Qb, Kb, Vt, ctx);

    gemm_bt<float><<<dim3(32, 32), 256, 0, stream>>>(ctx, Wdb, out, 4096, 4096, 4096);
}

// Round 2
// 987.764 us; speedup vs baseline: 1.1729x; 1.1729x over previous
//
#include <hip/hip_runtime.h>

typedef __bf16 bf16_t;
typedef __bf16 bf16x8 __attribute__((ext_vector_type(8)));
typedef __bf16 bf16x4 __attribute__((ext_vector_type(4)));
typedef __bf16 bf16x2 __attribute__((ext_vector_type(2)));
typedef float  f32x4  __attribute__((ext_vector_type(4)));
typedef float  f32x16 __attribute__((ext_vector_type(16)));
typedef unsigned int u32x4 __attribute__((ext_vector_type(4)));

#define MFMA16(a, b, c) __builtin_amdgcn_mfma_f32_16x16x32_bf16((a), (b), (c), 0, 0, 0)
#define MFMA32(a, b, c) __builtin_amdgcn_mfma_f32_32x32x16_bf16((a), (b), (c), 0, 0, 0)

__device__ __forceinline__ void async_load16(const void* g, void* l) {
    __builtin_amdgcn_global_load_lds(
        (const __attribute__((address_space(1))) void*)g,
        (__attribute__((address_space(3))) void*)l, 16, 0, 0);
}

__device__ __forceinline__ unsigned pack2(float a, float b) {
    bf16x2 t;
    t[0] = (bf16_t)a;
    t[1] = (bf16_t)b;
    return __builtin_bit_cast(unsigned, t);
}

// ---------------------------------------------------------------- fp32 -> bf16
__global__ void cvt_f32_to_bf16(const float* __restrict__ src, bf16_t* __restrict__ dst, int n) {
    int stride4 = gridDim.x * blockDim.x * 4;
    for (int j = (blockIdx.x * blockDim.x + threadIdx.x) * 4; j < n; j += stride4) {
        float4 v = *(const float4*)(src + j);
        bf16x4 o = { (bf16_t)v.x, (bf16_t)v.y, (bf16_t)v.z, (bf16_t)v.w };
        *(bf16x4*)(dst + j) = o;
    }
}

// ---------------------------------------------------------------- GEMM (B^T): C[m,n] = sum_k A[m,k]*B[n,k]
__device__ __forceinline__ void storeC(float* C, size_t idx, float v)  { C[idx] = v; }
__device__ __forceinline__ void storeC(bf16_t* C, size_t idx, float v) { C[idx] = (bf16_t)v; }

template <typename OT>
__global__ __launch_bounds__(256) void gemm_bt(const bf16_t* __restrict__ A,
                                               const bf16_t* __restrict__ B,
                                               OT* __restrict__ C,
                                               int M, int N, int K) {
    __shared__ __align__(16) bf16_t As[128][32];
    __shared__ __align__(16) bf16_t Bs[128][32];
    const int lane = threadIdx.x & 63;
    const int wid  = threadIdx.x >> 6;
    const int wr   = wid >> 1, wc = wid & 1;
    const int lrow = lane & 15, lhi = lane >> 4;
    const size_t m0 = (size_t)blockIdx.y * 128, n0 = (size_t)blockIdx.x * 128;
    const int srow = lane >> 2;
    const int scol = (lane & 3) * 8;

    const f32x4 vzero = {0.f, 0.f, 0.f, 0.f};
    f32x4 acc[4][4];
#pragma unroll
    for (int i = 0; i < 4; i++)
#pragma unroll
        for (int j = 0; j < 4; j++) acc[i][j] = vzero;

    for (int k0 = 0; k0 < K; k0 += 32) {
#pragma unroll
        for (int c = 0; c < 2; ++c) {
            int ra = wid * 32 + c * 16;
            async_load16(A + (m0 + ra + srow) * (size_t)K + k0 + scol, &As[ra][0]);
            async_load16(B + (n0 + ra + srow) * (size_t)K + k0 + scol, &Bs[ra][0]);
        }
        __syncthreads();
        bf16x8 af[4], bfr[4];
#pragma unroll
        for (int i = 0; i < 4; i++) af[i]  = *(const bf16x8*)(&As[wr * 64 + i * 16 + lrow][lhi * 8]);
#pragma unroll
        for (int j = 0; j < 4; j++) bfr[j] = *(const bf16x8*)(&Bs[wc * 64 + j * 16 + lrow][lhi * 8]);
#pragma unroll
        for (int i = 0; i < 4; i++)
#pragma unroll
            for (int j = 0; j < 4; j++)
                acc[i][j] = MFMA16(af[i], bfr[j], acc[i][j]);
        __syncthreads();
    }
#pragma unroll
    for (int i = 0; i < 4; i++)
#pragma unroll
        for (int j = 0; j < 4; j++)
#pragma unroll
            for (int r = 0; r < 4; r++) {
                size_t row = m0 + wr * 64 + i * 16 + lhi * 4 + r;
                size_t col = n0 + wc * 64 + j * 16 + lrow;
                storeC(C, row * (size_t)N + col, acc[i][j][r]);
            }
}

// ---------------------------------------------------------------- RoPE + scatter q/k
__global__ void rope_scatter(const bf16_t* __restrict__ fused, const int* __restrict__ pos_ids,
                             bf16_t* __restrict__ Q, bf16_t* __restrict__ Kb) {
    const int token = blockIdx.x;
    const int b = token >> 11, s = token & 2047;
    const int d = threadIdx.x;
    const float pos = (float)pos_ids[token];
    const float inv = __expf(-(float)d * (9.210340371976184f / 64.0f));
    float sn, c;
    sincosf(pos * inv, &sn, &c);
    const bf16_t* frow = fused + (size_t)token * 6144;
    for (int it = 0; it < 5; ++it) {
        int ss = it * 8 + threadIdx.y;
        int col;
        bf16_t* outp;
        if (ss < 32) {
            int h = ss, kv = h >> 2, gi = h & 3;
            col  = kv * 768 + gi * 128 + d;
            outp = Q + (((size_t)b * 32 + h) * 2048 + s) * 128 + d;
        } else {
            int kv = ss - 32;
            col  = kv * 768 + 512 + d;
            outp = Kb + (((size_t)b * 8 + kv) * 2048 + s) * 128 + d;
        }
        float x0 = (float)frow[col];
        float x1 = (float)frow[col + 64];
        outp[0]  = (bf16_t)(x0 * c - x1 * sn);
        outp[64] = (bf16_t)(x1 * c + x0 * sn);
    }
}

// ---------------------------------------------------------------- V transpose: fused v-cols -> Vt[b][kv][d][s]
__global__ void v_transpose(const bf16_t* __restrict__ fused, bf16_t* __restrict__ Vt) {
    __shared__ bf16_t tile[32][33];
    const int s0 = blockIdx.x * 32;
    const int d0 = blockIdx.y * 32;
    const int bk = blockIdx.z;
    const int b = bk >> 3, kv = bk & 7;
    const int col0 = kv * 768 + 640 + d0;
    const int tx = threadIdx.x, ty = threadIdx.y;
#pragma unroll
    for (int i = 0; i < 4; i++) {
        int sy = ty + i * 8;
        tile[sy][tx] = fused[((size_t)b * 2048 + s0 + sy) * 6144 + col0 + tx];
    }
    __syncthreads();
#pragma unroll
    for (int i = 0; i < 4; i++) {
        int dy = ty + i * 8;
        Vt[((size_t)bk * 128 + d0 + dy) * 2048 + s0 + tx] = tile[tx][dy];
    }
}

// ---------------------------------------------------------------- flash attention v2
// Swapped-operand 32x32 MFMA; softmax fully in-register.
// Q: [B][32][S][128], K: [B][8][S][128], Vt: [B][8][128][S], ctx: [B*S][4096]
// Per wave: one 32-row q-tile. S^T = mfma(K,Q): lane column = q-row (l31),
// rows kv in pattern cr(r,hi) = (r&3)+8*(r>>2)+4*hi.
// O^T = mfma(Vt,P): lane column = q-row -> rescale is per-lane scalar.
__global__ __launch_bounds__(256) void attn_fwd2(const bf16_t* __restrict__ Q,
                                                 const bf16_t* __restrict__ Kb,
                                                 const bf16_t* __restrict__ Vt,
                                                 bf16_t* __restrict__ ctx) {
    const int lane = threadIdx.x & 63;
    const int wid  = threadIdx.x >> 6;
    const int l31  = lane & 31;
    const int hi   = lane >> 5;
    const int qt = blockIdx.x * 4 + wid;   // 0..63
    const int h  = blockIdx.y, b = blockIdx.z;
    const int kvh = h >> 2;
    const int q0 = qt * 32;

    const bf16_t* qbase = Q  + (((size_t)b * 32 + h) * 2048 + q0) * 128;
    const bf16_t* kbase = Kb + (((size_t)b * 8 + kvh) * 2048) * 128;
    const bf16_t* vbase = Vt + (((size_t)b * 8 + kvh) * 128) * 2048;

    // Q B-fragments: lane holds Q[q0+l31][16*kc + 8*hi + j]
    bf16x8 qf[8];
#pragma unroll
    for (int kc = 0; kc < 8; ++kc)
        qf[kc] = *(const bf16x8*)(qbase + (size_t)l31 * 128 + kc * 16 + hi * 8);

    f32x16 o[4];
#pragma unroll
    for (int db = 0; db < 4; ++db)
#pragma unroll
        for (int r = 0; r < 16; ++r) o[db][r] = 0.f;

    float m = -1e30f, lsum = 0.f;
    const float sc = 0.08838834764831845f;  // 1/sqrt(128)

    for (int st = 0; st <= qt; ++st) {
        const int kv0 = st * 32;
        // --- S^T tile: rows kv, cols q ---
        f32x16 s;
#pragma unroll
        for (int r = 0; r < 16; ++r) s[r] = 0.f;
#pragma unroll
        for (int kc = 0; kc < 8; ++kc) {
            bf16x8 kf = *(const bf16x8*)(kbase + (size_t)(kv0 + l31) * 128 + kc * 16 + hi * 8);
            s = MFMA32(kf, qf[kc], s);
        }
        if (st == qt) {   // diagonal tile: causal mask
            const int qg = q0 + l31;
#pragma unroll
            for (int r = 0; r < 16; ++r) {
                int kvg = kv0 + (r & 3) + 8 * (r >> 2) + 4 * hi;
                if (kvg > qg) s[r] = -1e30f;
            }
        }
        // --- per-lane max over own 16 values, combine across half-pair ---
        float pmax = s[0];
#pragma unroll
        for (int r = 1; r < 16; ++r) pmax = fmaxf(pmax, s[r]);
        pmax = fmaxf(pmax, __shfl_xor(pmax, 32, 64));
        // --- defer-max: rescale only when max grows materially (e^8 headroom) ---
        if (pmax > m + 90.5f) {
            float corr = __expf((m - pmax) * sc);
            lsum *= corr;
#pragma unroll
            for (int db = 0; db < 4; ++db)
#pragma unroll
                for (int r = 0; r < 16; ++r) o[db][r] *= corr;
            m = pmax;
        }
        float p[16];
        float ps = 0.f;
#pragma unroll
        for (int r = 0; r < 16; ++r) { p[r] = __expf((s[r] - m) * sc); ps += p[r]; }
        lsum += ps;
        // --- build P B-fragments (col=q) and accumulate O^T = Vt * P ---
#pragma unroll
        for (int ks = 0; ks < 2; ++ks) {
            unsigned u0 = pack2(p[ks * 8 + 0], p[ks * 8 + 1]);  // kv {4hi, 4hi+1}
            unsigned u1 = pack2(p[ks * 8 + 2], p[ks * 8 + 3]);  // kv {4hi+2, 4hi+3}
            unsigned u2 = pack2(p[ks * 8 + 4], p[ks * 8 + 5]);  // kv {8+4hi, 8+4hi+1}
            unsigned u3 = pack2(p[ks * 8 + 6], p[ks * 8 + 7]);  // kv {8+4hi+2, ...}
            unsigned t0 = __shfl_xor(u0, 32, 64);
            unsigned t1 = __shfl_xor(u1, 32, 64);
            unsigned t2 = __shfl_xor(u2, 32, 64);
            unsigned t3 = __shfl_xor(u3, 32, 64);
            // B-frag word w needs kv = 16*ks + 8*hi + 2w (+1)
            u32x4 uw;
            uw[0] = hi ? t2 : u0;
            uw[1] = hi ? t3 : u1;
            uw[2] = hi ? u2 : t0;
            uw[3] = hi ? u3 : t1;
            bf16x8 pb = __builtin_bit_cast(bf16x8, uw);
#pragma unroll
            for (int db = 0; db < 4; ++db) {
                bf16x8 vf = *(const bf16x8*)(vbase + (size_t)(db * 32 + l31) * 2048
                                             + kv0 + ks * 16 + hi * 8);
                o[db] = MFMA32(vf, pb, o[db]);
            }
        }
    }
    lsum += __shfl_xor(lsum, 32, 64);
    const float inv = 1.0f / lsum;
    // O^T: lane column = q (l31); rows d = 32*db + 8*g + 4*hi + i  (reg = 4g+i)
    bf16_t* cb = ctx + ((size_t)(b * 2048 + q0 + l31)) * 4096 + h * 128;
#pragma unroll
    for (int db = 0; db < 4; ++db)
#pragma unroll
        for (int g = 0; g < 4; ++g) {
            bf16x4 w;
#pragma unroll
            for (int i = 0; i < 4; ++i) w[i] = (bf16_t)(o[db][g * 4 + i] * inv);
            *(bf16x4*)(cb + db * 32 + g * 8 + hi * 4) = w;
        }
}

// ---------------------------------------------------------------- launch
extern "C" void kernel_launch(void* const* d_in, const int* in_sizes, int n_in,
                              void* d_out, int out_size, void* d_ws, size_t ws_size,
                              hipStream_t stream) {
    const float* hs   = (const float*)d_in[0];
    const int*   pos  = (const int*)d_in[1];
    const float* wqkv = (const float*)d_in[2];
    const float* wd   = (const float*)d_in[3];
    float* out = (float*)d_out;
    char* ws = (char*)d_ws;

    bf16_t* Xb    = (bf16_t*)(ws + 0ull);           // later reused as Q
    bf16_t* Wqkvb = (bf16_t*)(ws + 33554432ull);
    bf16_t* Wdb   = (bf16_t*)(ws + 83886080ull);
    bf16_t* fused = (bf16_t*)(ws + 117440512ull);   // later reused as ctx
    bf16_t* Kb    = (bf16_t*)(ws + 167772160ull);
    bf16_t* Vt    = (bf16_t*)(ws + 176160768ull);
    bf16_t* Qb    = Xb;
    bf16_t* ctx   = fused;

    cvt_f32_to_bf16<<<2048, 256, 0, stream>>>(hs,   Xb,    16777216);
    cvt_f32_to_bf16<<<2048, 256, 0, stream>>>(wqkv, Wqkvb, 25165824);
    cvt_f32_to_bf16<<<2048, 256, 0, stream>>>(wd,   Wdb,   16777216);

    gemm_bt<bf16_t><<<dim3(48, 32), 256, 0, stream>>>(Xb, Wqkvb, fused, 4096, 6144, 4096);

    rope_scatter<<<4096, dim3(64, 8), 0, stream>>>(fused, pos, Qb, Kb);
    v_transpose<<<dim3(64, 4, 16), dim3(32, 8), 0, stream>>>(fused, Vt);

    attn_fwd2<<<dim3(16, 32, 2), 256, 0, stream>>>(Qb, Kb, Vt, ctx);

    gemm_bt<float><<<dim3(32, 32), 256, 0, stream>>>(ctx, Wdb, out, 4096, 4096, 4096);
}

// Round 3
// 806.474 us; speedup vs baseline: 1.4366x; 1.2248x over previous
//
#include <hip/hip_runtime.h>

typedef __bf16 bf16_t;
typedef __bf16 bf16x8 __attribute__((ext_vector_type(8)));
typedef __bf16 bf16x4 __attribute__((ext_vector_type(4)));
typedef __bf16 bf16x2 __attribute__((ext_vector_type(2)));
typedef float  f32x4  __attribute__((ext_vector_type(4)));
typedef float  f32x16 __attribute__((ext_vector_type(16)));
typedef unsigned int u32x4 __attribute__((ext_vector_type(4)));

#define MFMA16(a, b, c) __builtin_amdgcn_mfma_f32_16x16x32_bf16((a), (b), (c), 0, 0, 0)
#define MFMA32(a, b, c) __builtin_amdgcn_mfma_f32_32x32x16_bf16((a), (b), (c), 0, 0, 0)

__device__ __forceinline__ void async_load16(const void* g, void* l) {
    __builtin_amdgcn_global_load_lds(
        (const __attribute__((address_space(1))) void*)g,
        (__attribute__((address_space(3))) void*)l, 16, 0, 0);
}

__device__ __forceinline__ unsigned pack2(float a, float b) {
    bf16x2 t;
    t[0] = (bf16_t)a;
    t[1] = (bf16_t)b;
    return __builtin_bit_cast(unsigned, t);
}

// ---------------------------------------------------------------- fp32 -> bf16
__global__ void cvt_f32_to_bf16(const float* __restrict__ src, bf16_t* __restrict__ dst, int n) {
    int stride4 = gridDim.x * blockDim.x * 4;
    for (int j = (blockIdx.x * blockDim.x + threadIdx.x) * 4; j < n; j += stride4) {
        float4 v = *(const float4*)(src + j);
        bf16x4 o = { (bf16_t)v.x, (bf16_t)v.y, (bf16_t)v.z, (bf16_t)v.w };
        *(bf16x4*)(dst + j) = o;
    }
}

// ---------------------------------------------------------------- GEMM (B^T): C[m,n] = sum_k A[m,k]*B[n,k]
__device__ __forceinline__ void storeC(float* C, size_t idx, float v)  { C[idx] = v; }
__device__ __forceinline__ void storeC(bf16_t* C, size_t idx, float v) { C[idx] = (bf16_t)v; }

template <typename OT>
__global__ __launch_bounds__(256) void gemm_bt(const bf16_t* __restrict__ A,
                                               const bf16_t* __restrict__ B,
                                               OT* __restrict__ C,
                                               int M, int N, int K) {
    __shared__ __align__(16) bf16_t As[128][32];
    __shared__ __align__(16) bf16_t Bs[128][32];
    const int lane = threadIdx.x & 63;
    const int wid  = threadIdx.x >> 6;
    const int wr   = wid >> 1, wc = wid & 1;
    const int lrow = lane & 15, lhi = lane >> 4;
    const size_t m0 = (size_t)blockIdx.y * 128, n0 = (size_t)blockIdx.x * 128;
    const int srow = lane >> 2;
    const int scol = (lane & 3) * 8;

    const f32x4 vzero = {0.f, 0.f, 0.f, 0.f};
    f32x4 acc[4][4];
#pragma unroll
    for (int i = 0; i < 4; i++)
#pragma unroll
        for (int j = 0; j < 4; j++) acc[i][j] = vzero;

    for (int k0 = 0; k0 < K; k0 += 32) {
#pragma unroll
        for (int c = 0; c < 2; ++c) {
            int ra = wid * 32 + c * 16;
            async_load16(A + (m0 + ra + srow) * (size_t)K + k0 + scol, &As[ra][0]);
            async_load16(B + (n0 + ra + srow) * (size_t)K + k0 + scol, &Bs[ra][0]);
        }
        __syncthreads();
        bf16x8 af[4], bfr[4];
#pragma unroll
        for (int i = 0; i < 4; i++) af[i]  = *(const bf16x8*)(&As[wr * 64 + i * 16 + lrow][lhi * 8]);
#pragma unroll
        for (int j = 0; j < 4; j++) bfr[j] = *(const bf16x8*)(&Bs[wc * 64 + j * 16 + lrow][lhi * 8]);
#pragma unroll
        for (int i = 0; i < 4; i++)
#pragma unroll
            for (int j = 0; j < 4; j++)
                acc[i][j] = MFMA16(af[i], bfr[j], acc[i][j]);
        __syncthreads();
    }
#pragma unroll
    for (int i = 0; i < 4; i++)
#pragma unroll
        for (int j = 0; j < 4; j++)
#pragma unroll
            for (int r = 0; r < 4; r++) {
                size_t row = m0 + wr * 64 + i * 16 + lhi * 4 + r;
                size_t col = n0 + wc * 64 + j * 16 + lrow;
                storeC(C, row * (size_t)N + col, acc[i][j][r]);
            }
}

// ---------------------------------------------------------------- RoPE + scatter q/k
__global__ void rope_scatter(const bf16_t* __restrict__ fused, const int* __restrict__ pos_ids,
                             bf16_t* __restrict__ Q, bf16_t* __restrict__ Kb) {
    const int token = blockIdx.x;
    const int b = token >> 11, s = token & 2047;
    const int d = threadIdx.x;
    const float pos = (float)pos_ids[token];
    const float inv = __expf(-(float)d * (9.210340371976184f / 64.0f));
    float sn, c;
    sincosf(pos * inv, &sn, &c);
    const bf16_t* frow = fused + (size_t)token * 6144;
    for (int it = 0; it < 5; ++it) {
        int ss = it * 8 + threadIdx.y;
        int col;
        bf16_t* outp;
        if (ss < 32) {
            int h = ss, kv = h >> 2, gi = h & 3;
            col  = kv * 768 + gi * 128 + d;
            outp = Q + (((size_t)b * 32 + h) * 2048 + s) * 128 + d;
        } else {
            int kv = ss - 32;
            col  = kv * 768 + 512 + d;
            outp = Kb + (((size_t)b * 8 + kv) * 2048 + s) * 128 + d;
        }
        float x0 = (float)frow[col];
        float x1 = (float)frow[col + 64];
        outp[0]  = (bf16_t)(x0 * c - x1 * sn);
        outp[64] = (bf16_t)(x1 * c + x0 * sn);
    }
}

// ---------------------------------------------------------------- V transpose: fused v-cols -> Vt[b][kv][d][s]
__global__ void v_transpose(const bf16_t* __restrict__ fused, bf16_t* __restrict__ Vt) {
    __shared__ bf16_t tile[32][33];
    const int s0 = blockIdx.x * 32;
    const int d0 = blockIdx.y * 32;
    const int bk = blockIdx.z;
    const int b = bk >> 3, kv = bk & 7;
    const int col0 = kv * 768 + 640 + d0;
    const int tx = threadIdx.x, ty = threadIdx.y;
#pragma unroll
    for (int i = 0; i < 4; i++) {
        int sy = ty + i * 8;
        tile[sy][tx] = fused[((size_t)b * 2048 + s0 + sy) * 6144 + col0 + tx];
    }
    __syncthreads();
#pragma unroll
    for (int i = 0; i < 4; i++) {
        int dy = ty + i * 8;
        Vt[((size_t)bk * 128 + d0 + dy) * 2048 + s0 + tx] = tile[tx][dy];
    }
}

// ---------------------------------------------------------------- flash attention v3
// Swapped-operand 32x32 MFMA; softmax in-register; causal-pair load balance.
// One wave per block; wave handles q-tiles {p, 63-p} sequentially -> every
// wave does exactly 65 tile-iterations (perfect balance across 2048 blocks).
__global__ __launch_bounds__(64) void attn_fwd3(const bf16_t* __restrict__ Q,
                                                const bf16_t* __restrict__ Kb,
                                                const bf16_t* __restrict__ Vt,
                                                bf16_t* __restrict__ ctx) {
    const int lane = threadIdx.x;
    const int l31  = lane & 31;
    const int hi   = lane >> 5;
    const int bid  = blockIdx.x;
    const int b    = bid & 1;
    const int h    = (bid >> 1) & 31;
    const int p    = bid >> 6;           // 0..31
    const int kvh  = h >> 2;

    const bf16_t* kbase = Kb + (((size_t)b * 8 + kvh) * 2048) * 128;
    const bf16_t* vbase = Vt + (((size_t)b * 8 + kvh) * 128) * 2048;
    const float sc = 0.08838834764831845f;  // 1/sqrt(128)

    for (int t = 0; t < 2; ++t) {
        const int qt = t ? (63 - p) : p;
        const int q0 = qt * 32;
        const bf16_t* qbase = Q + (((size_t)b * 32 + h) * 2048 + q0) * 128;

        // Q B-fragments: lane holds Q[q0+l31][16*kc + 8*hi + j]
        bf16x8 qf[8];
#pragma unroll
        for (int kc = 0; kc < 8; ++kc)
            qf[kc] = *(const bf16x8*)(qbase + (size_t)l31 * 128 + kc * 16 + hi * 8);

        f32x16 o[4];
#pragma unroll
        for (int db = 0; db < 4; ++db)
#pragma unroll
            for (int r = 0; r < 16; ++r) o[db][r] = 0.f;

        float m = -1e30f, lsum = 0.f;

        for (int st = 0; st <= qt; ++st) {
            const int kv0 = st * 32;
            const bf16_t* krow = kbase + (size_t)(kv0 + l31) * 128 + hi * 8;
            // issue all K fragment loads up front
            bf16x8 kf[8];
#pragma unroll
            for (int kc = 0; kc < 8; ++kc) kf[kc] = *(const bf16x8*)(krow + kc * 16);
            // two independent accumulation chains (halved MFMA dep latency)
            f32x16 sa, sb;
#pragma unroll
            for (int r = 0; r < 16; ++r) { sa[r] = 0.f; sb[r] = 0.f; }
#pragma unroll
            for (int kc = 0; kc < 4; ++kc) {
                sa = MFMA32(kf[2 * kc],     qf[2 * kc],     sa);
                sb = MFMA32(kf[2 * kc + 1], qf[2 * kc + 1], sb);
            }
            f32x16 s;
#pragma unroll
            for (int r = 0; r < 16; ++r) s[r] = sa[r] + sb[r];

            if (st == qt) {   // diagonal tile: causal mask
                const int qg = q0 + l31;
#pragma unroll
                for (int r = 0; r < 16; ++r) {
                    int kvg = kv0 + (r & 3) + 8 * (r >> 2) + 4 * hi;
                    if (kvg > qg) s[r] = -1e30f;
                }
            }
            // row max (lane-local 16 + half-pair combine)
            float mx01 = fmaxf(s[0], s[1]);
#pragma unroll
            for (int r = 2; r < 16; r += 2) mx01 = fmaxf(mx01, fmaxf(s[r], s[r + 1]));
            float pmax = fmaxf(mx01, __shfl_xor(mx01, 32, 64));
            // defer-max: rescale only when max grows materially (e^8 headroom)
            if (pmax > m + 90.5f) {
                float corr = __expf((m - pmax) * sc);
                lsum *= corr;
#pragma unroll
                for (int db = 0; db < 4; ++db)
#pragma unroll
                    for (int r = 0; r < 16; ++r) o[db][r] *= corr;
                m = pmax;
            }
            // exp in place + 4-chain tree sum
            float ps4[4] = {0.f, 0.f, 0.f, 0.f};
#pragma unroll
            for (int r = 0; r < 16; ++r) {
                float e = __expf((s[r] - m) * sc);
                s[r] = e;
                ps4[r & 3] += e;
            }
            lsum += (ps4[0] + ps4[1]) + (ps4[2] + ps4[3]);
            // build P B-fragments (col=q) and accumulate O^T = Vt * P
#pragma unroll
            for (int ks = 0; ks < 2; ++ks) {
                unsigned u0 = pack2(s[ks * 8 + 0], s[ks * 8 + 1]);
                unsigned u1 = pack2(s[ks * 8 + 2], s[ks * 8 + 3]);
                unsigned u2 = pack2(s[ks * 8 + 4], s[ks * 8 + 5]);
                unsigned u3 = pack2(s[ks * 8 + 6], s[ks * 8 + 7]);
                unsigned t0 = __shfl_xor(u0, 32, 64);
                unsigned t1 = __shfl_xor(u1, 32, 64);
                unsigned t2 = __shfl_xor(u2, 32, 64);
                unsigned t3 = __shfl_xor(u3, 32, 64);
                u32x4 uw;
                uw[0] = hi ? t2 : u0;
                uw[1] = hi ? t3 : u1;
                uw[2] = hi ? u2 : t0;
                uw[3] = hi ? u3 : t1;
                bf16x8 pb = __builtin_bit_cast(bf16x8, uw);
#pragma unroll
                for (int db = 0; db < 4; ++db) {
                    bf16x8 vf = *(const bf16x8*)(vbase + (size_t)(db * 32 + l31) * 2048
                                                 + kv0 + ks * 16 + hi * 8);
                    o[db] = MFMA32(vf, pb, o[db]);
                }
            }
        }
        lsum += __shfl_xor(lsum, 32, 64);
        const float inv = 1.0f / lsum;
        bf16_t* cb = ctx + ((size_t)(b * 2048 + q0 + l31)) * 4096 + h * 128;
#pragma unroll
        for (int db = 0; db < 4; ++db)
#pragma unroll
            for (int g = 0; g < 4; ++g) {
                bf16x4 w;
#pragma unroll
                for (int i = 0; i < 4; ++i) w[i] = (bf16_t)(o[db][g * 4 + i] * inv);
                *(bf16x4*)(cb + db * 32 + g * 8 + hi * 4) = w;
            }
    }
}

// ---------------------------------------------------------------- launch
extern "C" void kernel_launch(void* const* d_in, const int* in_sizes, int n_in,
                              void* d_out, int out_size, void* d_ws, size_t ws_size,
                              hipStream_t stream) {
    const float* hs   = (const float*)d_in[0];
    const int*   pos  = (const int*)d_in[1];
    const float* wqkv = (const float*)d_in[2];
    const float* wd   = (const float*)d_in[3];
    float* out = (float*)d_out;
    char* ws = (char*)d_ws;

    bf16_t* Xb    = (bf16_t*)(ws + 0ull);           // later reused as Q
    bf16_t* Wqkvb = (bf16_t*)(ws + 33554432ull);
    bf16_t* Wdb   = (bf16_t*)(ws + 83886080ull);
    bf16_t* fused = (bf16_t*)(ws + 117440512ull);   // later reused as ctx
    bf16_t* Kb    = (bf16_t*)(ws + 167772160ull);
    bf16_t* Vt    = (bf16_t*)(ws + 176160768ull);
    bf16_t* Qb    = Xb;
    bf16_t* ctx   = fused;

    cvt_f32_to_bf16<<<2048, 256, 0, stream>>>(hs,   Xb,    16777216);
    cvt_f32_to_bf16<<<2048, 256, 0, stream>>>(wqkv, Wqkvb, 25165824);
    cvt_f32_to_bf16<<<2048, 256, 0, stream>>>(wd,   Wdb,   16777216);

    gemm_bt<bf16_t><<<dim3(48, 32), 256, 0, stream>>>(Xb, Wqkvb, fused, 4096, 6144, 4096);

    rope_scatter<<<4096, dim3(64, 8), 0, stream>>>(fused, pos, Qb, Kb);
    v_transpose<<<dim3(64, 4, 16), dim3(32, 8), 0, stream>>>(fused, Vt);

    attn_fwd3<<<2048, 64, 0, stream>>>(Qb, Kb, Vt, ctx);

    gemm_bt<float><<<dim3(32, 32), 256, 0, stream>>>(ctx, Wdb, out, 4096, 4096, 4096);
}

// Round 4
// 721.278 us; speedup vs baseline: 1.6062x; 1.1181x over previous
//
#include <hip/hip_runtime.h>

typedef __bf16 bf16_t;
typedef __bf16 bf16x8 __attribute__((ext_vector_type(8)));
typedef __bf16 bf16x4 __attribute__((ext_vector_type(4)));
typedef __bf16 bf16x2 __attribute__((ext_vector_type(2)));
typedef float  f32x4  __attribute__((ext_vector_type(4)));
typedef float  f32x16 __attribute__((ext_vector_type(16)));
typedef unsigned int u32x4 __attribute__((ext_vector_type(4)));

#define MFMA16(a, b, c) __builtin_amdgcn_mfma_f32_16x16x32_bf16((a), (b), (c), 0, 0, 0)
#define MFMA32(a, b, c) __builtin_amdgcn_mfma_f32_32x32x16_bf16((a), (b), (c), 0, 0, 0)

__device__ __forceinline__ void async_load16(const void* g, void* l) {
    __builtin_amdgcn_global_load_lds(
        (const __attribute__((address_space(1))) void*)g,
        (__attribute__((address_space(3))) void*)l, 16, 0, 0);
}

__device__ __forceinline__ unsigned pack2(float a, float b) {
    bf16x2 t;
    t[0] = (bf16_t)a;
    t[1] = (bf16_t)b;
    return __builtin_bit_cast(unsigned, t);
}

// ---------------------------------------------------------------- fp32 -> bf16
__global__ void cvt_f32_to_bf16(const float* __restrict__ src, bf16_t* __restrict__ dst, int n) {
    int stride4 = gridDim.x * blockDim.x * 4;
    for (int j = (blockIdx.x * blockDim.x + threadIdx.x) * 4; j < n; j += stride4) {
        float4 v = *(const float4*)(src + j);
        bf16x4 o = { (bf16_t)v.x, (bf16_t)v.y, (bf16_t)v.z, (bf16_t)v.w };
        *(bf16x4*)(dst + j) = o;
    }
}

__device__ __forceinline__ void storeC(float* C, size_t idx, float v)  { C[idx] = v; }
__device__ __forceinline__ void storeC(bf16_t* C, size_t idx, float v) { C[idx] = (bf16_t)v; }

// ---------------------------------------------------------------- 256x256 8-phase GEMM (B^T)
// C[m,n] = sum_k A[m,k] * B[n,k].  BM=BN=256, BK=64, 8 waves.
// T2: 3-bit column XOR swizzle; T3/T4: per-phase half-tile staging w/ counted vmcnt;
// T5: setprio around MFMA clusters.  Requires M%256==0, N%256==0, K%64==0, grid%8==0.
template <typename OT>
__global__ __launch_bounds__(512, 2) void gemm256(const bf16_t* __restrict__ A,
                                                  const bf16_t* __restrict__ B,
                                                  OT* __restrict__ C,
                                                  int M, int N, int K) {
    __shared__ __align__(16) bf16_t lds[2][2][2][128][64];  // [buf][A=0/B=1][half][row][col]
    const int tid  = threadIdx.x;
    const int lane = tid & 63;
    const int wid  = tid >> 6;
    const int lrow = lane & 15, lhi = lane >> 4;
    const int wrow = (wid >> 2) * 64;   // wave row offset within 128-row quadrant-half
    const int wcol = (wid & 3) * 32;    // wave col offset within 128-col quadrant-half
    const int NT = K >> 6;
    const int nbx = N >> 8;

    // XCD-aware bijective swizzle (grid % 8 == 0)
    const int nwg = gridDim.x;
    const int w = ((int)blockIdx.x & 7) * (nwg >> 3) + ((int)blockIdx.x >> 3);
    const size_t m0 = (size_t)(w / nbx) * 256;
    const size_t n0 = (size_t)(w % nbx) * 256;

    // read-side column swizzle (elems): col ^= f(row&7), bits {5,4,3}
    const int cmask = ((lrow & 1) << 5) | ((lrow & 2) << 3) | ((lrow & 4) << 1);
    const int cK0 = (lhi * 8) ^ cmask;        // k-sub 0
    const int cK1 = (32 + lhi * 8) ^ cmask;   // k-sub 1
    // stage-side: thread covers row r8 = lane>>3 (mod 8), phys col (lane&7)*8
    const int r8 = lane >> 3;
    const int gcol = ((lane & 7) * 8) ^ (((r8 & 1) << 5) | ((r8 & 2) << 3) | ((r8 & 4) << 1));

    auto stage = [&](const bf16_t* srcBase, bf16_t* region) {
#pragma unroll
        for (int c = 0; c < 2; ++c)
            async_load16(srcBase + (size_t)(c * 64 + wid * 8 + r8) * K + gcol,
                         region + c * 4096 + wid * 512);
    };

    int buf = 0;
    bf16x8 af[2][4];        // A frags (current quadrant-half), [ksub][i]
    bf16x8 b0f[2][2], b1f[2][2];

    auto loadA = [&](int mh) {
#pragma unroll
        for (int i = 0; i < 4; ++i) {
            const bf16_t* rp = &lds[buf][0][mh][wrow + i * 16 + lrow][0];
            af[0][i] = *(const bf16x8*)(rp + cK0);
            af[1][i] = *(const bf16x8*)(rp + cK1);
        }
    };
    auto loadB = [&](int nh, bf16x8 (&bf)[2][2]) {
#pragma unroll
        for (int j = 0; j < 2; ++j) {
            const bf16_t* rp = &lds[buf][1][nh][wcol + j * 16 + lrow][0];
            bf[0][j] = *(const bf16x8*)(rp + cK0);
            bf[1][j] = *(const bf16x8*)(rp + cK1);
        }
    };
    auto mmacc = [&](f32x4 (&acc)[4][2], bf16x8 (&bf)[2][2]) {
#pragma unroll
        for (int kk = 0; kk < 2; ++kk)
#pragma unroll
            for (int i = 0; i < 4; ++i)
#pragma unroll
                for (int j = 0; j < 2; ++j)
                    acc[i][j] = MFMA16(af[kk][i], bf[kk][j], acc[i][j]);
    };

    f32x4 a00[4][2], a01[4][2], a10[4][2], a11[4][2];
    const f32x4 vz = {0.f, 0.f, 0.f, 0.f};
#pragma unroll
    for (int i = 0; i < 4; ++i)
#pragma unroll
        for (int j = 0; j < 2; ++j) { a00[i][j] = vz; a01[i][j] = vz; a10[i][j] = vz; a11[i][j] = vz; }

    const bf16_t* Am = A + m0 * K;
    const bf16_t* Bn = B + n0 * K;

    // prologue: tile0 {A0,B0,B1,A1} -> buf0; tile1 {A0,B0} -> buf1 (exact issue order!)
    stage(Am,                     &lds[0][0][0][0][0]);
    stage(Bn,                     &lds[0][1][0][0][0]);
    stage(Bn + (size_t)128 * K,   &lds[0][1][1][0][0]);
    stage(Am + (size_t)128 * K,   &lds[0][0][1][0][0]);
    stage(Am + 64,                &lds[1][0][0][0][0]);
    stage(Bn + 64,                &lds[1][1][0][0][0]);
    asm volatile("s_waitcnt vmcnt(4)" ::: "memory");
    __builtin_amdgcn_s_barrier();

    for (int u = 0; u < NT; ++u, buf ^= 1) {
        const bf16_t* Ak1 = Am + (size_t)(u + 1) * 64;
        const bf16_t* Bk1 = Bn + (size_t)(u + 1) * 64;
        // ---- phase 0: quadrant (0,0)  reads A0,B0
        loadA(0);
        loadB(0, b0f);
        if (u + 1 < NT) stage(Bk1 + (size_t)128 * K, &lds[buf ^ 1][1][1][0][0]);
        __builtin_amdgcn_s_barrier();
        asm volatile("s_waitcnt lgkmcnt(0)" ::: "memory");
        __builtin_amdgcn_s_setprio(1);
        mmacc(a00, b0f);
        __builtin_amdgcn_s_setprio(0);
        __builtin_amdgcn_s_barrier();
        // ---- phase 1: quadrant (0,1)  reads B1 (A0 frags reused)
        loadB(1, b1f);
        if (u + 1 < NT) stage(Ak1 + (size_t)128 * K, &lds[buf ^ 1][0][1][0][0]);
        __builtin_amdgcn_s_barrier();
        asm volatile("s_waitcnt lgkmcnt(0)" ::: "memory");
        __builtin_amdgcn_s_setprio(1);
        mmacc(a01, b1f);
        __builtin_amdgcn_s_setprio(0);
        __builtin_amdgcn_s_barrier();
        // ---- phase 2: quadrant (1,0)  reads A1 (B0 frags reused)
        loadA(1);
        if (u + 2 < NT) stage(Am + (size_t)(u + 2) * 64, &lds[buf][0][0][0][0]);
        __builtin_amdgcn_s_barrier();
        asm volatile("s_waitcnt lgkmcnt(0)" ::: "memory");
        __builtin_amdgcn_s_setprio(1);
        mmacc(a10, b0f);
        __builtin_amdgcn_s_setprio(0);
        __builtin_amdgcn_s_barrier();
        // ---- phase 3: quadrant (1,1)  (A1,B1 frags reused)
        if (u + 2 < NT) stage(Bn + (size_t)(u + 2) * 64, &lds[buf][1][0][0][0]);
        __builtin_amdgcn_s_barrier();
        __builtin_amdgcn_s_setprio(1);
        mmacc(a11, b1f);
        __builtin_amdgcn_s_setprio(0);
        if (u == NT - 2)     asm volatile("s_waitcnt vmcnt(0)" ::: "memory");
        else if (u < NT - 2) asm volatile("s_waitcnt vmcnt(4)" ::: "memory");
        __builtin_amdgcn_s_barrier();
    }

    auto storeQ = [&](f32x4 (&acc)[4][2], int mq, int nq) {
#pragma unroll
        for (int i = 0; i < 4; ++i)
#pragma unroll
            for (int j = 0; j < 2; ++j)
#pragma unroll
                for (int r = 0; r < 4; ++r) {
                    size_t row = m0 + mq * 128 + wrow + i * 16 + lhi * 4 + r;
                    size_t col = n0 + nq * 128 + wcol + j * 16 + lrow;
                    storeC(C, row * (size_t)N + col, acc[i][j][r]);
                }
    };
    storeQ(a00, 0, 0); storeQ(a01, 0, 1); storeQ(a10, 1, 0); storeQ(a11, 1, 1);
}

// ---------------------------------------------------------------- RoPE + scatter q/k
__global__ void rope_scatter(const bf16_t* __restrict__ fused, const int* __restrict__ pos_ids,
                             bf16_t* __restrict__ Q, bf16_t* __restrict__ Kb) {
    const int token = blockIdx.x;
    const int b = token >> 11, s = token & 2047;
    const int d = threadIdx.x;
    const float pos = (float)pos_ids[token];
    const float inv = __expf(-(float)d * (9.210340371976184f / 64.0f));
    float sn, c;
    sincosf(pos * inv, &sn, &c);
    const bf16_t* frow = fused + (size_t)token * 6144;
    for (int it = 0; it < 5; ++it) {
        int ss = it * 8 + threadIdx.y;
        int col;
        bf16_t* outp;
        if (ss < 32) {
            int h = ss, kv = h >> 2, gi = h & 3;
            col  = kv * 768 + gi * 128 + d;
            outp = Q + (((size_t)b * 32 + h) * 2048 + s) * 128 + d;
        } else {
            int kv = ss - 32;
            col  = kv * 768 + 512 + d;
            outp = Kb + (((size_t)b * 8 + kv) * 2048 + s) * 128 + d;
        }
        float x0 = (float)frow[col];
        float x1 = (float)frow[col + 64];
        outp[0]  = (bf16_t)(x0 * c - x1 * sn);
        outp[64] = (bf16_t)(x1 * c + x0 * sn);
    }
}

// ---------------------------------------------------------------- V transpose: fused v-cols -> Vt[b][kv][d][s]
__global__ void v_transpose(const bf16_t* __restrict__ fused, bf16_t* __restrict__ Vt) {
    __shared__ bf16_t tile[32][33];
    const int s0 = blockIdx.x * 32;
    const int d0 = blockIdx.y * 32;
    const int bk = blockIdx.z;
    const int b = bk >> 3, kv = bk & 7;
    const int col0 = kv * 768 + 640 + d0;
    const int tx = threadIdx.x, ty = threadIdx.y;
#pragma unroll
    for (int i = 0; i < 4; i++) {
        int sy = ty + i * 8;
        tile[sy][tx] = fused[((size_t)b * 2048 + s0 + sy) * 6144 + col0 + tx];
    }
    __syncthreads();
#pragma unroll
    for (int i = 0; i < 4; i++) {
        int dy = ty + i * 8;
        Vt[((size_t)bk * 128 + d0 + dy) * 2048 + s0 + tx] = tile[tx][dy];
    }
}

// ---------------------------------------------------------------- flash attention v3
// Swapped-operand 32x32 MFMA; softmax in-register; causal-pair load balance.
__global__ __launch_bounds__(64) void attn_fwd3(const bf16_t* __restrict__ Q,
                                                const bf16_t* __restrict__ Kb,
                                                const bf16_t* __restrict__ Vt,
                                                bf16_t* __restrict__ ctx) {
    const int lane = threadIdx.x;
    const int l31  = lane & 31;
    const int hi   = lane >> 5;
    const int bid  = blockIdx.x;
    const int b    = bid & 1;
    const int h    = (bid >> 1) & 31;
    const int p    = bid >> 6;           // 0..31
    const int kvh  = h >> 2;

    const bf16_t* kbase = Kb + (((size_t)b * 8 + kvh) * 2048) * 128;
    const bf16_t* vbase = Vt + (((size_t)b * 8 + kvh) * 128) * 2048;
    const float sc = 0.08838834764831845f;  // 1/sqrt(128)

    for (int t = 0; t < 2; ++t) {
        const int qt = t ? (63 - p) : p;
        const int q0 = qt * 32;
        const bf16_t* qbase = Q + (((size_t)b * 32 + h) * 2048 + q0) * 128;

        bf16x8 qf[8];
#pragma unroll
        for (int kc = 0; kc < 8; ++kc)
            qf[kc] = *(const bf16x8*)(qbase + (size_t)l31 * 128 + kc * 16 + hi * 8);

        f32x16 o[4];
#pragma unroll
        for (int db = 0; db < 4; ++db)
#pragma unroll
            for (int r = 0; r < 16; ++r) o[db][r] = 0.f;

        float m = -1e30f, lsum = 0.f;

        for (int st = 0; st <= qt; ++st) {
            const int kv0 = st * 32;
            const bf16_t* krow = kbase + (size_t)(kv0 + l31) * 128 + hi * 8;
            bf16x8 kf[8];
#pragma unroll
            for (int kc = 0; kc < 8; ++kc) kf[kc] = *(const bf16x8*)(krow + kc * 16);
            f32x16 sa, sb;
#pragma unroll
            for (int r = 0; r < 16; ++r) { sa[r] = 0.f; sb[r] = 0.f; }
#pragma unroll
            for (int kc = 0; kc < 4; ++kc) {
                sa = MFMA32(kf[2 * kc],     qf[2 * kc],     sa);
                sb = MFMA32(kf[2 * kc + 1], qf[2 * kc + 1], sb);
            }
            f32x16 s;
#pragma unroll
            for (int r = 0; r < 16; ++r) s[r] = sa[r] + sb[r];

            if (st == qt) {
                const int qg = q0 + l31;
#pragma unroll
                for (int r = 0; r < 16; ++r) {
                    int kvg = kv0 + (r & 3) + 8 * (r >> 2) + 4 * hi;
                    if (kvg > qg) s[r] = -1e30f;
                }
            }
            float mx01 = fmaxf(s[0], s[1]);
#pragma unroll
            for (int r = 2; r < 16; r += 2) mx01 = fmaxf(mx01, fmaxf(s[r], s[r + 1]));
            float pmax = fmaxf(mx01, __shfl_xor(mx01, 32, 64));
            if (pmax > m + 90.5f) {
                float corr = __expf((m - pmax) * sc);
                lsum *= corr;
#pragma unroll
                for (int db = 0; db < 4; ++db)
#pragma unroll
                    for (int r = 0; r < 16; ++r) o[db][r] *= corr;
                m = pmax;
            }
            float ps4[4] = {0.f, 0.f, 0.f, 0.f};
#pragma unroll
            for (int r = 0; r < 16; ++r) {
                float e = __expf((s[r] - m) * sc);
                s[r] = e;
                ps4[r & 3] += e;
            }
            lsum += (ps4[0] + ps4[1]) + (ps4[2] + ps4[3]);
#pragma unroll
            for (int ks = 0; ks < 2; ++ks) {
                unsigned u0 = pack2(s[ks * 8 + 0], s[ks * 8 + 1]);
                unsigned u1 = pack2(s[ks * 8 + 2], s[ks * 8 + 3]);
                unsigned u2 = pack2(s[ks * 8 + 4], s[ks * 8 + 5]);
                unsigned u3 = pack2(s[ks * 8 + 6], s[ks * 8 + 7]);
                unsigned t0 = __shfl_xor(u0, 32, 64);
                unsigned t1 = __shfl_xor(u1, 32, 64);
                unsigned t2 = __shfl_xor(u2, 32, 64);
                unsigned t3 = __shfl_xor(u3, 32, 64);
                u32x4 uw;
                uw[0] = hi ? t2 : u0;
                uw[1] = hi ? t3 : u1;
                uw[2] = hi ? u2 : t0;
                uw[3] = hi ? u3 : t1;
                bf16x8 pb = __builtin_bit_cast(bf16x8, uw);
#pragma unroll
                for (int db = 0; db < 4; ++db) {
                    bf16x8 vf = *(const bf16x8*)(vbase + (size_t)(db * 32 + l31) * 2048
                                                 + kv0 + ks * 16 + hi * 8);
                    o[db] = MFMA32(vf, pb, o[db]);
                }
            }
        }
        lsum += __shfl_xor(lsum, 32, 64);
        const float inv = 1.0f / lsum;
        bf16_t* cb = ctx + ((size_t)(b * 2048 + q0 + l31)) * 4096 + h * 128;
#pragma unroll
        for (int db = 0; db < 4; ++db)
#pragma unroll
            for (int g = 0; g < 4; ++g) {
                bf16x4 w;
#pragma unroll
                for (int i = 0; i < 4; ++i) w[i] = (bf16_t)(o[db][g * 4 + i] * inv);
                *(bf16x4*)(cb + db * 32 + g * 8 + hi * 4) = w;
            }
    }
}

// ---------------------------------------------------------------- launch
extern "C" void kernel_launch(void* const* d_in, const int* in_sizes, int n_in,
                              void* d_out, int out_size, void* d_ws, size_t ws_size,
                              hipStream_t stream) {
    const float* hs   = (const float*)d_in[0];
    const int*   pos  = (const int*)d_in[1];
    const float* wqkv = (const float*)d_in[2];
    const float* wd   = (const float*)d_in[3];
    float* out = (float*)d_out;
    char* ws = (char*)d_ws;

    bf16_t* Xb    = (bf16_t*)(ws + 0ull);           // later reused as Q
    bf16_t* Wqkvb = (bf16_t*)(ws + 33554432ull);
    bf16_t* Wdb   = (bf16_t*)(ws + 83886080ull);
    bf16_t* fused = (bf16_t*)(ws + 117440512ull);   // later reused as ctx
    bf16_t* Kb    = (bf16_t*)(ws + 167772160ull);
    bf16_t* Vt    = (bf16_t*)(ws + 176160768ull);
    bf16_t* Qb    = Xb;
    bf16_t* ctx   = fused;

    cvt_f32_to_bf16<<<2048, 256, 0, stream>>>(hs,   Xb,    16777216);
    cvt_f32_to_bf16<<<2048, 256, 0, stream>>>(wqkv, Wqkvb, 25165824);
    cvt_f32_to_bf16<<<2048, 256, 0, stream>>>(wd,   Wdb,   16777216);

    gemm256<bf16_t><<<384, 512, 0, stream>>>(Xb, Wqkvb, fused, 4096, 6144, 4096);

    rope_scatter<<<4096, dim3(64, 8), 0, stream>>>(fused, pos, Qb, Kb);
    v_transpose<<<dim3(64, 4, 16), dim3(32, 8), 0, stream>>>(fused, Vt);

    attn_fwd3<<<2048, 64, 0, stream>>>(Qb, Kb, Vt, ctx);

    gemm256<float><<<256, 512, 0, stream>>>(ctx, Wdb, out, 4096, 4096, 4096);
}